// Round 1
// baseline (165.342 us; speedup 1.0000x reference)
//
#include <hip/hip_runtime.h>
#include <math.h>

// Problem constants (from reference): x is (B=64, C=64, H=64, W=64) fp32.
#define BDIM 64
#define CDIM 64
#define HWN  4096            // H*W
#define NROWS (BDIM * HWN)   // 262144 spatial rows
#define EPSV 1e-5f

// ws layout (floats):
//  [0 .. 63]   per-channel sums (accumulated by k_chansum)
//  [64 ..127]  mu
//  [128]       var_sum (sum of d^2)
#define WS_SUMS 0
#define WS_MU   64
#define WS_VAR  128

// ---------------- K1: per-channel sums ----------------
// One block per (b,c) plane (4096 contiguous floats). grid = B*C = 4096.
__global__ __launch_bounds__(256) void k_chansum(const float* __restrict__ x,
                                                 float* __restrict__ ws) {
    const int plane = blockIdx.x;          // b*C + c
    const int c = plane & (CDIM - 1);
    const float4* p4 = reinterpret_cast<const float4*>(x + (size_t)plane * HWN);
    float s = 0.f;
#pragma unroll
    for (int i = 0; i < HWN / 4 / 256; ++i) {
        float4 v = p4[threadIdx.x + i * 256];
        s += (v.x + v.y) + (v.z + v.w);
    }
    // wave reduce (64-lane), then cross-wave via LDS
    for (int off = 32; off; off >>= 1) s += __shfl_down(s, off, 64);
    __shared__ float red[4];
    const int lane = threadIdx.x & 63, wid = threadIdx.x >> 6;
    if (lane == 0) red[wid] = s;
    __syncthreads();
    if (threadIdx.x == 0)
        atomicAdd(&ws[WS_SUMS + c], (red[0] + red[1]) + (red[2] + red[3]));
}

// ---------------- K2: mu from sums (1 wave) ----------------
__global__ void k_mu(float* __restrict__ ws) {
    const int c = threadIdx.x;             // 64 threads = 1 wave
    const float m = ws[WS_SUMS + c] * (1.0f / (float)NROWS);
    float mm = (c == 0) ? m * m : -m * m;  // m0^2 - sum(m[1:]^2)
    for (int off = 32; off; off >>= 1) mm += __shfl_down(mm, off, 64);
    mm = __shfl(mm, 0, 64);
    ws[WS_MU + c] = m / sqrtf(fmaxf(mm, EPSV));
}

// ---------------- K3: alpha -> d^2 global sum ----------------
__global__ __launch_bounds__(256) void k_var(const float* __restrict__ x,
                                             float* __restrict__ ws) {
    __shared__ float smu[CDIM];
    if (threadIdx.x < CDIM) smu[threadIdx.x] = ws[WS_MU + threadIdx.x];
    __syncthreads();

    const int n = blockIdx.x * 256 + threadIdx.x;   // row id < NROWS
    const int b = n >> 12;                          // n / HWN
    const int hw = n & (HWN - 1);
    const float* p = x + (size_t)b * CDIM * HWN + hw;

    float alpha = p[0] * smu[0];
#pragma unroll
    for (int c = 1; c < CDIM; ++c) alpha -= p[(size_t)c * HWN] * smu[c];
    alpha = fmaxf(alpha, 1.0f + EPSV);
    const float d = acoshf(alpha);
    float dd = d * d;

    for (int off = 32; off; off >>= 1) dd += __shfl_down(dd, off, 64);
    __shared__ float red[4];
    const int lane = threadIdx.x & 63, wid = threadIdx.x >> 6;
    if (lane == 0) red[wid] = dd;
    __syncthreads();
    if (threadIdx.x == 0)
        atomicAdd(&ws[WS_VAR], (red[0] + red[1]) + (red[2] + red[3]));
}

// ---------------- K4: final transform + output ----------------
__global__ __launch_bounds__(256) void k_out(const float* __restrict__ x,
                                             const float* __restrict__ gamma,
                                             const float* __restrict__ beta,
                                             float* __restrict__ out,
                                             const float* __restrict__ ws) {
    __shared__ float smu[CDIM], sg[CDIM], sb[CDIM];
    if (threadIdx.x < CDIM) {
        smu[threadIdx.x] = ws[WS_MU + threadIdx.x];
        sg[threadIdx.x] = (threadIdx.x >= 1) ? gamma[threadIdx.x - 1] : 0.f;
        sb[threadIdx.x] = (threadIdx.x >= 1) ? beta[threadIdx.x - 1] : 0.f;
    }
    __syncthreads();

    const float var = ws[WS_VAR] * (1.0f / (float)NROWS);
    const float inv_sv = 1.0f / (sqrtf(var) + EPSV);

    const int n = blockIdx.x * 256 + threadIdx.x;
    const int b = n >> 12;
    const int hw = n & (HWN - 1);
    const size_t base = (size_t)b * CDIM * HWN + hw;
    const float* p = x + base;

    // Keep the whole channel row in registers (static indexing only).
    float xr[CDIM];
#pragma unroll
    for (int c = 0; c < CDIM; ++c) xr[c] = p[(size_t)c * HWN];

    float alpha = xr[0] * smu[0];
#pragma unroll
    for (int c = 1; c < CDIM; ++c) alpha -= xr[c] * smu[c];
    alpha = fmaxf(alpha, 1.0f + EPSV);
    const float d = acoshf(alpha);
    const float coef = d / sqrtf(alpha * alpha - 1.0f);

    const float v0 = coef * (xr[0] - alpha * smu[0]);
    const float k = v0 / (1.0f + smu[0]);

    float* op = out + base;
    float s2 = 0.f;
#pragma unroll
    for (int c = 1; c < CDIM; ++c) {
        const float v = coef * (xr[c] - alpha * smu[c]);
        const float vo = v - k * smu[c];            // mu_plus_o[c] == mu[c] for c>=1
        const float s = sg[c] * vo * inv_sv + sb[c];
        s2 += s * s;
        op[(size_t)c * HWN] = s;
    }
    op[0] = sqrtf(1.0f + s2);                        // t channel
}

extern "C" void kernel_launch(void* const* d_in, const int* in_sizes, int n_in,
                              void* d_out, int out_size, void* d_ws, size_t ws_size,
                              hipStream_t stream) {
    const float* x     = (const float*)d_in[0];
    const float* gamma = (const float*)d_in[1];
    const float* beta  = (const float*)d_in[2];
    float* out = (float*)d_out;
    float* ws  = (float*)d_ws;

    // ws is poisoned with 0xAA before every timed launch: zero the accumulators.
    hipMemsetAsync(ws, 0, 1024, stream);

    k_chansum<<<BDIM * CDIM, 256, 0, stream>>>(x, ws);
    k_mu<<<1, 64, 0, stream>>>(ws);
    k_var<<<NROWS / 256, 256, 0, stream>>>(x, ws);
    k_out<<<NROWS / 256, 256, 0, stream>>>(x, gamma, beta, out, ws);
}

// Round 3
// 138.319 us; speedup vs baseline: 1.1954x; 1.1954x over previous
//
#include <hip/hip_runtime.h>
#include <math.h>

// x is (B=64, C=64, H=64, W=64) fp32, NCHW.
#define BDIM 64
#define CDIM 64
#define HWN  4096            // H*W
#define NROWS (BDIM * HWN)   // 262144 spatial rows
#define CHSTRIDE (CDIM * HWN)
#define EPSV 1e-5f

// ws layout (floats), no atomics anywhere:
//  [0 .. 4095]          per-(b,c)-plane sums (plane = b*64 + c)   <- K1
//  [4096 .. 4351]       per-block d^2 partials (256 blocks)       <- K3
//  [8192 .. +NROWS)     alpha per row                             <- K3
//  [COEF .. +NROWS)     coef per row                              <- K3
#define DD_OFF    4096
#define ALPHA_OFF 8192
#define COEF_OFF  (ALPHA_OFF + NROWS)

// ---------------- K1: per-plane sums ----------------
__global__ __launch_bounds__(256) void k_chansum(const float* __restrict__ x,
                                                 float* __restrict__ ws) {
    const int plane = blockIdx.x;          // b*C + c
    const float4* p4 = reinterpret_cast<const float4*>(x + (size_t)plane * HWN);
    float s = 0.f;
#pragma unroll
    for (int i = 0; i < HWN / 4 / 256; ++i) {
        float4 v = p4[threadIdx.x + i * 256];
        s += (v.x + v.y) + (v.z + v.w);
    }
    for (int off = 32; off; off >>= 1) s += __shfl_down(s, off, 64);
    __shared__ float red[4];
    const int lane = threadIdx.x & 63, wid = threadIdx.x >> 6;
    if (lane == 0) red[wid] = s;
    __syncthreads();
    if (threadIdx.x == 0) ws[plane] = (red[0] + red[1]) + (red[2] + red[3]);
}

// Per-block redundant mu recompute from plane sums (16 KB of L2-hot reads).
// stmp must hold 256 floats; smu gets mu[64]. Ends with __syncthreads().
__device__ __forceinline__ void compute_mu(const float* __restrict__ ws,
                                           float* smu, float* stmp) {
    const int t = threadIdx.x, c = t & 63, g = t >> 6;
    float m = 0.f;
#pragma unroll
    for (int b = 0; b < BDIM / 4; ++b) m += ws[(g * (BDIM / 4) + b) * CDIM + c];
    stmp[g * 64 + c] = m;
    __syncthreads();
    if (t < 64) {
        const float msum = (stmp[c] + stmp[64 + c]) + (stmp[128 + c] + stmp[192 + c]);
        const float mval = msum * (1.0f / (float)NROWS);
        float mm = (c == 0) ? mval * mval : -mval * mval;   // m0^2 - sum(m[1:]^2)
        for (int off = 32; off; off >>= 1) mm += __shfl_down(mm, off, 64);
        mm = __shfl(mm, 0, 64);
        smu[c] = mval / sqrtf(fmaxf(mm, EPSV));
    }
    __syncthreads();
}

// ---------------- K3: alpha/coef per row + d^2 partials ----------------
// 256 blocks x 256 threads; each thread owns 4 consecutive rows (float4 over hw).
__global__ __launch_bounds__(256) void k_alpha(const float* __restrict__ x,
                                               float* __restrict__ ws) {
    __shared__ float smu[64];
    __shared__ float stmp[256];
    compute_mu(ws, smu, stmp);

    const int tid = blockIdx.x * 256 + threadIdx.x;   // 0..65535
    const int n0 = tid * 4;
    const int b = n0 >> 12;
    const int hw = n0 & (HWN - 1);
    const float* p = x + (size_t)b * CHSTRIDE + hw;

    float al[4];
    {
        const float4 v = *reinterpret_cast<const float4*>(p);
        const float m0 = smu[0];
        al[0] = v.x * m0; al[1] = v.y * m0; al[2] = v.z * m0; al[3] = v.w * m0;
    }
#pragma unroll
    for (int c = 1; c < CDIM; ++c) {
        const float4 v = *reinterpret_cast<const float4*>(p + (size_t)c * HWN);
        const float m = smu[c];
        al[0] -= v.x * m; al[1] -= v.y * m; al[2] -= v.z * m; al[3] -= v.w * m;
    }
    float dd = 0.f, co[4];
#pragma unroll
    for (int j = 0; j < 4; ++j) {
        al[j] = fmaxf(al[j], 1.0f + EPSV);
        const float d = acoshf(al[j]);
        dd += d * d;
        co[j] = d / sqrtf(al[j] * al[j] - 1.0f);
    }
    *reinterpret_cast<float4*>(&ws[ALPHA_OFF + n0]) = make_float4(al[0], al[1], al[2], al[3]);
    *reinterpret_cast<float4*>(&ws[COEF_OFF + n0])  = make_float4(co[0], co[1], co[2], co[3]);

    for (int off = 32; off; off >>= 1) dd += __shfl_down(dd, off, 64);
    __shared__ float red[4];
    const int lane = threadIdx.x & 63, wid = threadIdx.x >> 6;
    if (lane == 0) red[wid] = dd;
    __syncthreads();
    if (threadIdx.x == 0)
        ws[DD_OFF + blockIdx.x] = (red[0] + red[1]) + (red[2] + red[3]);
}

// ---------------- K4: streaming output transform ----------------
// 256 blocks x 256 threads; each thread owns 4 consecutive rows (float4 over hw).
__global__ __launch_bounds__(256) void k_out(const float* __restrict__ x,
                                             const float* __restrict__ gamma,
                                             const float* __restrict__ beta,
                                             float* __restrict__ out,
                                             const float* __restrict__ ws) {
    __shared__ float smu[64], sg[64], sb[64];
    __shared__ float stmp[256];
    compute_mu(ws, smu, stmp);

    // var: every block re-reduces the 256 per-block d^2 partials.
    float pd = ws[DD_OFF + threadIdx.x];
    for (int off = 32; off; off >>= 1) pd += __shfl_down(pd, off, 64);
    const int lane = threadIdx.x & 63, wid = threadIdx.x >> 6;
    if (lane == 0) stmp[wid] = pd;
    if (threadIdx.x < 64) {
        sg[threadIdx.x] = (threadIdx.x >= 1) ? gamma[threadIdx.x - 1] : 0.f;
        sb[threadIdx.x] = (threadIdx.x >= 1) ? beta[threadIdx.x - 1] : 0.f;
    }
    __syncthreads();
    const float varsum = (stmp[0] + stmp[1]) + (stmp[2] + stmp[3]);
    const float var = varsum * (1.0f / (float)NROWS);
    const float inv_sv = 1.0f / (sqrtf(var) + EPSV);

    const int tid = blockIdx.x * 256 + threadIdx.x;
    const int n0 = tid * 4;
    const int b = n0 >> 12;
    const int hw = n0 & (HWN - 1);
    const size_t base = (size_t)b * CHSTRIDE + hw;
    const float* p = x + base;
    float* op = out + base;

    float al[4], co[4];
    {
        const float4 a4 = *reinterpret_cast<const float4*>(&ws[ALPHA_OFF + n0]);
        const float4 c4 = *reinterpret_cast<const float4*>(&ws[COEF_OFF + n0]);
        al[0] = a4.x; al[1] = a4.y; al[2] = a4.z; al[3] = a4.w;
        co[0] = c4.x; co[1] = c4.y; co[2] = c4.z; co[3] = c4.w;
    }

    float kk[4];
    {
        const float4 v = *reinterpret_cast<const float4*>(p);
        const float xv[4] = {v.x, v.y, v.z, v.w};
        const float m0 = smu[0];
        const float inv1m0 = 1.0f / (1.0f + m0);
#pragma unroll
        for (int j = 0; j < 4; ++j)
            kk[j] = co[j] * (xv[j] - al[j] * m0) * inv1m0;   // v0/(1+mu0)
    }

    float s2[4] = {0.f, 0.f, 0.f, 0.f};
#pragma unroll
    for (int c = 1; c < CDIM; ++c) {
        const float4 v = *reinterpret_cast<const float4*>(p + (size_t)c * HWN);
        const float xv[4] = {v.x, v.y, v.z, v.w};
        const float m = smu[c], g = sg[c], bb = sb[c];
        float sv[4];
#pragma unroll
        for (int j = 0; j < 4; ++j) {
            const float vv = co[j] * (xv[j] - al[j] * m);
            const float vo = vv - kk[j] * m;          // mu_plus_o[c]==mu[c], c>=1
            sv[j] = g * vo * inv_sv + bb;
            s2[j] += sv[j] * sv[j];
        }
        *reinterpret_cast<float4*>(op + (size_t)c * HWN) =
            make_float4(sv[0], sv[1], sv[2], sv[3]);
    }
    *reinterpret_cast<float4*>(op) =
        make_float4(sqrtf(1.0f + s2[0]), sqrtf(1.0f + s2[1]),
                    sqrtf(1.0f + s2[2]), sqrtf(1.0f + s2[3]));
}

extern "C" void kernel_launch(void* const* d_in, const int* in_sizes, int n_in,
                              void* d_out, int out_size, void* d_ws, size_t ws_size,
                              hipStream_t stream) {
    const float* x     = (const float*)d_in[0];
    const float* gamma = (const float*)d_in[1];
    const float* beta  = (const float*)d_in[2];
    float* out = (float*)d_out;
    float* ws  = (float*)d_ws;

    k_chansum<<<BDIM * CDIM, 256, 0, stream>>>(x, ws);
    k_alpha<<<NROWS / 4 / 256, 256, 0, stream>>>(x, ws);
    k_out<<<NROWS / 4 / 256, 256, 0, stream>>>(x, gamma, beta, out, ws);
}

// Round 4
// 137.769 us; speedup vs baseline: 1.2001x; 1.0040x over previous
//
#include <hip/hip_runtime.h>
#include <math.h>

// x is (B=64, C=64, H=64, W=64) fp32, NCHW.
#define BDIM 64
#define CDIM 64
#define HWN  4096            // H*W
#define NROWS (BDIM * HWN)   // 262144 spatial rows
#define CHSTRIDE (CDIM * HWN)
#define EPSV 1e-5f

#define ROWBLOCKS (NROWS / 256)   // 1024 blocks for the per-row passes

// ws layout (floats), no atomics anywhere:
//  [0 .. 4095]          per-(b,c)-plane sums (plane = b*64 + c)   <- K1
//  [4096 .. 5119]       per-block d^2 partials (1024 blocks)      <- K3
//  [8192 .. +NROWS)     alpha per row                             <- K3
//  [COEF .. +NROWS)     coef per row                              <- K3
#define DD_OFF    4096
#define ALPHA_OFF 8192
#define COEF_OFF  (ALPHA_OFF + NROWS)

// ---------------- K1: per-plane sums ----------------
__global__ __launch_bounds__(256) void k_chansum(const float* __restrict__ x,
                                                 float* __restrict__ ws) {
    const int plane = blockIdx.x;          // b*C + c
    const float4* p4 = reinterpret_cast<const float4*>(x + (size_t)plane * HWN);
    float s = 0.f;
#pragma unroll
    for (int i = 0; i < HWN / 4 / 256; ++i) {
        float4 v = p4[threadIdx.x + i * 256];
        s += (v.x + v.y) + (v.z + v.w);
    }
    for (int off = 32; off; off >>= 1) s += __shfl_down(s, off, 64);
    __shared__ float red[4];
    const int lane = threadIdx.x & 63, wid = threadIdx.x >> 6;
    if (lane == 0) red[wid] = s;
    __syncthreads();
    if (threadIdx.x == 0) ws[plane] = (red[0] + red[1]) + (red[2] + red[3]);
}

// Per-block redundant mu recompute from plane sums (16 KB of L2-hot reads).
// stmp must hold 256 floats; smu gets mu[64]. Ends with __syncthreads().
__device__ __forceinline__ void compute_mu(const float* __restrict__ ws,
                                           float* smu, float* stmp) {
    const int t = threadIdx.x, c = t & 63, g = t >> 6;
    float m = 0.f;
#pragma unroll
    for (int b = 0; b < BDIM / 4; ++b) m += ws[(g * (BDIM / 4) + b) * CDIM + c];
    stmp[g * 64 + c] = m;
    __syncthreads();
    if (t < 64) {
        const float msum = (stmp[c] + stmp[64 + c]) + (stmp[128 + c] + stmp[192 + c]);
        const float mval = msum * (1.0f / (float)NROWS);
        float mm = (c == 0) ? mval * mval : -mval * mval;   // m0^2 - sum(m[1:]^2)
        for (int off = 32; off; off >>= 1) mm += __shfl_down(mm, off, 64);
        mm = __shfl(mm, 0, 64);
        smu[c] = mval / sqrtf(fmaxf(mm, EPSV));
    }
    __syncthreads();
}

// ---------------- K3: alpha/coef per row + d^2 partials ----------------
// 1024 blocks x 256 threads; 1 row per thread (scalar channel loads).
__global__ __launch_bounds__(256) void k_alpha(const float* __restrict__ x,
                                               float* __restrict__ ws) {
    __shared__ float smu[64];
    __shared__ float stmp[256];
    compute_mu(ws, smu, stmp);

    const int n = blockIdx.x * 256 + threadIdx.x;   // row id
    const int b = n >> 12;
    const int hw = n & (HWN - 1);
    const float* p = x + (size_t)b * CHSTRIDE + hw;

    float alpha = p[0] * smu[0];
#pragma unroll
    for (int c = 1; c < CDIM; ++c) alpha -= p[(size_t)c * HWN] * smu[c];
    alpha = fmaxf(alpha, 1.0f + EPSV);
    const float d = acoshf(alpha);
    const float coef = d / sqrtf(alpha * alpha - 1.0f);
    ws[ALPHA_OFF + n] = alpha;
    ws[COEF_OFF + n]  = coef;

    float dd = d * d;
    for (int off = 32; off; off >>= 1) dd += __shfl_down(dd, off, 64);
    __shared__ float red[4];
    const int lane = threadIdx.x & 63, wid = threadIdx.x >> 6;
    if (lane == 0) red[wid] = dd;
    __syncthreads();
    if (threadIdx.x == 0)
        ws[DD_OFF + blockIdx.x] = (red[0] + red[1]) + (red[2] + red[3]);
}

// ---------------- K4: streaming output transform ----------------
// 1024 blocks x 256 threads; 1 row per thread (scalar channel loads/stores).
__global__ __launch_bounds__(256) void k_out(const float* __restrict__ x,
                                             const float* __restrict__ gamma,
                                             const float* __restrict__ beta,
                                             float* __restrict__ out,
                                             const float* __restrict__ ws) {
    __shared__ float smu[64], sg[64], sb[64];
    __shared__ float stmp[256];
    compute_mu(ws, smu, stmp);

    // var: every block re-reduces the 1024 per-block d^2 partials.
    float pd = ws[DD_OFF + threadIdx.x] + ws[DD_OFF + 256 + threadIdx.x] +
               ws[DD_OFF + 512 + threadIdx.x] + ws[DD_OFF + 768 + threadIdx.x];
    for (int off = 32; off; off >>= 1) pd += __shfl_down(pd, off, 64);
    const int lane = threadIdx.x & 63, wid = threadIdx.x >> 6;
    if (lane == 0) stmp[wid] = pd;
    if (threadIdx.x < 64) {
        sg[threadIdx.x] = (threadIdx.x >= 1) ? gamma[threadIdx.x - 1] : 0.f;
        sb[threadIdx.x] = (threadIdx.x >= 1) ? beta[threadIdx.x - 1] : 0.f;
    }
    __syncthreads();
    const float varsum = (stmp[0] + stmp[1]) + (stmp[2] + stmp[3]);
    const float var = varsum * (1.0f / (float)NROWS);
    const float inv_sv = 1.0f / (sqrtf(var) + EPSV);

    const int n = blockIdx.x * 256 + threadIdx.x;
    const int b = n >> 12;
    const int hw = n & (HWN - 1);
    const size_t base = (size_t)b * CHSTRIDE + hw;
    const float* p = x + base;
    float* op = out + base;

    const float al = ws[ALPHA_OFF + n];
    const float co = ws[COEF_OFF + n];
    const float m0 = smu[0];
    const float kk = co * (p[0] - al * m0) / (1.0f + m0);   // v0/(1+mu0)

    float s2 = 0.f;
#pragma unroll
    for (int c = 1; c < CDIM; ++c) {
        const float xv = p[(size_t)c * HWN];
        const float m = smu[c];
        const float v = co * (xv - al * m);
        const float vo = v - kk * m;             // mu_plus_o[c]==mu[c], c>=1
        const float s = sg[c] * vo * inv_sv + sb[c];
        s2 += s * s;
        op[(size_t)c * HWN] = s;
    }
    op[0] = sqrtf(1.0f + s2);                    // t channel
}

extern "C" void kernel_launch(void* const* d_in, const int* in_sizes, int n_in,
                              void* d_out, int out_size, void* d_ws, size_t ws_size,
                              hipStream_t stream) {
    const float* x     = (const float*)d_in[0];
    const float* gamma = (const float*)d_in[1];
    const float* beta  = (const float*)d_in[2];
    float* out = (float*)d_out;
    float* ws  = (float*)d_ws;

    k_chansum<<<BDIM * CDIM, 256, 0, stream>>>(x, ws);
    k_alpha<<<ROWBLOCKS, 256, 0, stream>>>(x, ws);
    k_out<<<ROWBLOCKS, 256, 0, stream>>>(x, gamma, beta, out, ws);
}